// Round 1
// baseline (968.575 us; speedup 1.0000x reference)
//
#include <hip/hip_runtime.h>

// ---------------------------------------------------------------------------
// classifier_selective_ts_with_g — MI355X bf16-MFMA implementation (round 0)
//
// Pipeline:
//  K0 cvt_weights : fc1/fc2/fcs/gfcs/l1 weights fp32 -> bf16 (ws)
//  K1 feau        : fea_u = sum_m x3            -> bf16 (4096,768)
//  K2 gemm<RELUBN>: h = bn(relu(fea_u@fc1^T+b)) -> bf16 (4096,384)
//  K3 gemm<BIAS>  : fea_z = h@fc2^T+b           -> bf16 (4096,384)
//  K4 gemm<BIAS>  : vec = fea_z@fcs^T+b         -> bf16 (4096,7296)
//  K5 att_gemm    : att[m] = [vec_m | g_m]@gfcs_m^T + b -> bf16 (4096,19,768)
//  K6 softmax_feav: softmax over m + weighted x sum -> fea_v bf16 (4096,768)
//  K7 gemm<RELUBN>: h1 = bn(relu(fea_v@l1^T+b)) -> bf16 (4096,128)
//  K8 l2          : h2 = bn(relu(h1@l2^T+b))    -> f32 (4096,32)
//  K9 l3          : out = h2@l3^T+b             -> f32 (4096,20)
// ---------------------------------------------------------------------------

typedef unsigned short u16;
typedef unsigned int u32;
typedef float f32x4 __attribute__((ext_vector_type(4)));
typedef __bf16 bf16x8 __attribute__((ext_vector_type(8)));

#define GPTR(p) ((const __attribute__((address_space(1))) void*)(p))
#define SPTR(p) ((__attribute__((address_space(3))) void*)(p))

__device__ __forceinline__ u16 f2bf(float f) {
    u32 u = __float_as_uint(f);
    u += 0x7fffu + ((u >> 16) & 1u);   // RNE; inputs are finite
    return (u16)(u >> 16);
}
__device__ __forceinline__ float bf2f(u16 h) {
    return __uint_as_float(((u32)h) << 16);
}

#define BNRS 0.9999950000374997f  // 1/sqrt(1+1e-5)

#define EPI_BIAS    0
#define EPI_RELU_BN 1

// ---------------------------------------------------------------------------
// Generic C = A @ B^T + bias (+relu+bn) ; A: M x K bf16, B: N x K bf16,
// C: M x N bf16. Tiles: BM=BN=128, BK=32, 4 waves of 64x64, 16x16x32 MFMA.
// M, N, K must be multiples of 128/128/32 (true for all our shapes).
// ---------------------------------------------------------------------------
template <int EPI>
__global__ __launch_bounds__(256)
void gemm_bf16_kernel(const u16* __restrict__ A, const u16* __restrict__ B,
                      const float* __restrict__ bias,
                      const float* __restrict__ bnG, const float* __restrict__ bnB,
                      u16* __restrict__ C, int K, int N)
{
    constexpr int BK = 32;
    __shared__ __align__(16) u16 lA[128 * BK];
    __shared__ __align__(16) u16 lB[128 * BK];

    const int tid  = threadIdx.x;
    const int wave = tid >> 6;
    const int lane = tid & 63;
    const int bm   = blockIdx.x * 128;
    const int bn   = blockIdx.y * 128;
    const int wm   = (wave >> 1) * 64;
    const int wn   = (wave & 1) * 64;
    const int rl   = lane & 15;
    const int qk   = (lane >> 4) * 8;

    f32x4 acc[4][4] = {};

    const u16* Ab = A + (size_t)bm * K;
    const u16* Bb = B + (size_t)bn * K;

    for (int k0 = 0; k0 < K; k0 += BK) {
#pragma unroll
        for (int r = 0; r < 2; ++r) {
            const int c   = r * 256 + wave * 64 + lane;   // chunk of 8 bf16
            const int row = c >> 2;
            const int kc  = (c & 3) << 3;
            const u16* sa = Ab + (size_t)row * K + (k0 + kc);
            const u16* sb = Bb + (size_t)row * K + (k0 + kc);
            __builtin_amdgcn_global_load_lds(GPTR(sa), SPTR(&lA[(r * 256 + wave * 64) * 8]), 16, 0, 0);
            __builtin_amdgcn_global_load_lds(GPTR(sb), SPTR(&lB[(r * 256 + wave * 64) * 8]), 16, 0, 0);
        }
        __syncthreads();

        bf16x8 af[4], bfr[4];
#pragma unroll
        for (int i = 0; i < 4; ++i) af[i]  = *(const bf16x8*)&lA[(wm + i * 16 + rl) * BK + qk];
#pragma unroll
        for (int j = 0; j < 4; ++j) bfr[j] = *(const bf16x8*)&lB[(wn + j * 16 + rl) * BK + qk];
#pragma unroll
        for (int i = 0; i < 4; ++i)
#pragma unroll
            for (int j = 0; j < 4; ++j)
                acc[i][j] = __builtin_amdgcn_mfma_f32_16x16x32_bf16(af[i], bfr[j], acc[i][j], 0, 0, 0);
        __syncthreads();
    }

    const int q4 = (lane >> 4) * 4;
#pragma unroll
    for (int j = 0; j < 4; ++j) {
        const int col = bn + wn + j * 16 + rl;
        const float bsv = bias[col];
        float scl = 1.f, sft = 0.f;
        if constexpr (EPI == EPI_RELU_BN) { scl = bnG[col] * BNRS; sft = bnB[col]; }
#pragma unroll
        for (int i = 0; i < 4; ++i) {
            const int row0 = bm + wm + i * 16 + q4;
#pragma unroll
            for (int r = 0; r < 4; ++r) {
                float v = acc[i][j][r] + bsv;
                if constexpr (EPI == EPI_RELU_BN) v = fmaxf(v, 0.f) * scl + sft;
                C[(size_t)(row0 + r) * N + col] = f2bf(v);
            }
        }
    }
}

// ---------------------------------------------------------------------------
// att[m] = cat(vec[:,m,:], g3[:,m,:]) @ gfcs_W[m]^T + gfcs_b[m]
// A is virtual: k<384 from vec (bf16), k>=384 from g (fp32, cvt on the fly).
// grid: (4096/128, 768/128, 19)
// ---------------------------------------------------------------------------
__global__ __launch_bounds__(256)
void att_gemm_kernel(const u16* __restrict__ vec, const float* __restrict__ g,
                     const u16* __restrict__ W, const float* __restrict__ bias,
                     u16* __restrict__ att)
{
    constexpr int BK = 32, K = 1152;
    __shared__ __align__(16) u16 lA[128 * BK];
    __shared__ __align__(16) u16 lB[128 * BK];

    const int m    = blockIdx.z;
    const int tid  = threadIdx.x;
    const int wave = tid >> 6;
    const int lane = tid & 63;
    const int bm   = blockIdx.x * 128;
    const int bn   = blockIdx.y * 128;
    const int wm   = (wave >> 1) * 64;
    const int wn   = (wave & 1) * 64;
    const int rl   = lane & 15;
    const int qk   = (lane >> 4) * 8;

    f32x4 acc[4][4] = {};

    const u16*  Av = vec + (size_t)bm * 7296 + m * 384;
    const float* Ag = g  + (size_t)bm * 14592 + m * 768;
    const u16*  Bb = W  + (size_t)m * 884736 + (size_t)bn * K;

    for (int k0 = 0; k0 < K; k0 += BK) {
        if (k0 < 384) {
#pragma unroll
            for (int r = 0; r < 2; ++r) {
                const int c   = r * 256 + wave * 64 + lane;
                const int row = c >> 2;
                const int kc  = (c & 3) << 3;
                const u16* sa = Av + (size_t)row * 7296 + (k0 + kc);
                __builtin_amdgcn_global_load_lds(GPTR(sa), SPTR(&lA[(r * 256 + wave * 64) * 8]), 16, 0, 0);
            }
        } else {
#pragma unroll
            for (int r = 0; r < 2; ++r) {
                const int c   = r * 256 + tid;
                const int row = c >> 2;
                const int kc  = (c & 3) << 3;
                const float* sf = Ag + (size_t)row * 14592 + (k0 - 384 + kc);
                const float4 f0 = *(const float4*)sf;
                const float4 f1 = *(const float4*)(sf + 4);
                uint4 pk;
                pk.x = (u32)f2bf(f0.x) | ((u32)f2bf(f0.y) << 16);
                pk.y = (u32)f2bf(f0.z) | ((u32)f2bf(f0.w) << 16);
                pk.z = (u32)f2bf(f1.x) | ((u32)f2bf(f1.y) << 16);
                pk.w = (u32)f2bf(f1.z) | ((u32)f2bf(f1.w) << 16);
                *(uint4*)&lA[c * 8] = pk;
            }
        }
#pragma unroll
        for (int r = 0; r < 2; ++r) {
            const int c   = r * 256 + wave * 64 + lane;
            const int row = c >> 2;
            const int kc  = (c & 3) << 3;
            const u16* sb = Bb + (size_t)row * K + (k0 + kc);
            __builtin_amdgcn_global_load_lds(GPTR(sb), SPTR(&lB[(r * 256 + wave * 64) * 8]), 16, 0, 0);
        }
        __syncthreads();

        bf16x8 af[4], bfr[4];
#pragma unroll
        for (int i = 0; i < 4; ++i) af[i]  = *(const bf16x8*)&lA[(wm + i * 16 + rl) * BK + qk];
#pragma unroll
        for (int j = 0; j < 4; ++j) bfr[j] = *(const bf16x8*)&lB[(wn + j * 16 + rl) * BK + qk];
#pragma unroll
        for (int i = 0; i < 4; ++i)
#pragma unroll
            for (int j = 0; j < 4; ++j)
                acc[i][j] = __builtin_amdgcn_mfma_f32_16x16x32_bf16(af[i], bfr[j], acc[i][j], 0, 0, 0);
        __syncthreads();
    }

    const int q4 = (lane >> 4) * 4;
#pragma unroll
    for (int j = 0; j < 4; ++j) {
        const int col = bn + wn + j * 16 + rl;
        const float bsv = bias[(size_t)m * 768 + col];
#pragma unroll
        for (int i = 0; i < 4; ++i) {
            const int row0 = bm + wm + i * 16 + q4;
#pragma unroll
            for (int r = 0; r < 4; ++r) {
                att[(size_t)(row0 + r) * 14592 + m * 768 + col] = f2bf(acc[i][j][r] + bsv);
            }
        }
    }
}

// ---------------------------------------------------------------------------
// weights fp32 -> bf16, 5 segments in one grid
// ---------------------------------------------------------------------------
__global__ __launch_bounds__(256)
void cvt_weights_kernel(const float* __restrict__ s0, const float* __restrict__ s1,
                        const float* __restrict__ s2, const float* __restrict__ s3,
                        const float* __restrict__ s4,
                        u16* __restrict__ d0, u16* __restrict__ d1, u16* __restrict__ d2,
                        u16* __restrict__ d3, u16* __restrict__ d4)
{
    const int i = blockIdx.x * 256 + threadIdx.x;
    const float* s; u16* d; int off;
    if (i < 294912)        { s = s0; d = d0; off = i; }
    else if (i < 442368)   { s = s1; d = d1; off = i - 294912; }
    else if (i < 3244032)  { s = s2; d = d2; off = i - 442368; }
    else if (i < 20054016) { s = s3; d = d3; off = i - 3244032; }
    else                   { s = s4; d = d4; off = i - 20054016; }
    d[off] = f2bf(s[off]);
}

__global__ __launch_bounds__(256)
void feau_kernel(const float* __restrict__ x, u16* __restrict__ feau)
{
    const int b = blockIdx.x;
    const int o = blockIdx.y * 256 + threadIdx.x;
    const float* xp = x + (size_t)b * 14592 + o;
    float s = 0.f;
#pragma unroll
    for (int m = 0; m < 19; ++m) s += xp[m * 768];
    feau[(size_t)b * 768 + o] = f2bf(s);
}

__global__ __launch_bounds__(256)
void softmax_feav_kernel(const u16* __restrict__ att, const float* __restrict__ x,
                         u16* __restrict__ feav)
{
    const int b = blockIdx.x;
    const int o = blockIdx.y * 256 + threadIdx.x;
    const u16* ap   = att + (size_t)b * 14592 + o;
    const float* xp = x   + (size_t)b * 14592 + o;
    float l[19];
    float mx = -1e30f;
#pragma unroll
    for (int m = 0; m < 19; ++m) { l[m] = bf2f(ap[m * 768]); mx = fmaxf(mx, l[m]); }
    float s = 0.f;
#pragma unroll
    for (int m = 0; m < 19; ++m) { const float e = __expf(l[m] - mx); l[m] = e; s += e; }
    const float inv = 1.f / s;
    float a = 0.f;
#pragma unroll
    for (int m = 0; m < 19; ++m) a += xp[m * 768] * l[m];
    feav[(size_t)b * 768 + o] = f2bf(a * inv);
}

__global__ __launch_bounds__(256)
void l2_kernel(const u16* __restrict__ h1, const float* __restrict__ W,
               const float* __restrict__ bias, const float* __restrict__ bg,
               const float* __restrict__ bb, float* __restrict__ h2)
{
    const int idx = blockIdx.x * 256 + threadIdx.x;   // 4096*32
    const int b = idx >> 5, n = idx & 31;
    const u16* hp  = h1 + (size_t)b * 128;
    const float* wp = W + n * 128;
    float a = bias[n];
#pragma unroll 8
    for (int k = 0; k < 128; ++k) a += bf2f(hp[k]) * wp[k];
    a = fmaxf(a, 0.f) * (bg[n] * BNRS) + bb[n];
    h2[idx] = a;
}

__global__ __launch_bounds__(256)
void l3_kernel(const float* __restrict__ h2, const float* __restrict__ W,
               const float* __restrict__ bias, float* __restrict__ out)
{
    const int idx = blockIdx.x * 256 + threadIdx.x;   // 4096*20
    const int b = idx / 20, n = idx - b * 20;
    const float* hp = h2 + (size_t)b * 32;
    const float* wp = W + n * 32;
    float a = bias[n];
#pragma unroll
    for (int k = 0; k < 32; ++k) a += hp[k] * wp[k];
    out[idx] = a;
}

// ---------------------------------------------------------------------------
extern "C" void kernel_launch(void* const* d_in, const int* in_sizes, int n_in,
                              void* d_out, int out_size, void* d_ws, size_t ws_size,
                              hipStream_t stream)
{
    const float* x      = (const float*)d_in[0];
    const float* g      = (const float*)d_in[1];
    const float* fc1_W  = (const float*)d_in[2];
    const float* fc1_b  = (const float*)d_in[3];
    const float* bn1_g  = (const float*)d_in[4];
    const float* bn1_b  = (const float*)d_in[5];
    const float* fc2_W  = (const float*)d_in[6];
    const float* fc2_b  = (const float*)d_in[7];
    const float* fcs_W  = (const float*)d_in[8];
    const float* fcs_b  = (const float*)d_in[9];
    const float* gfcs_W = (const float*)d_in[10];
    const float* gfcs_b = (const float*)d_in[11];
    const float* l1_W   = (const float*)d_in[12];
    const float* l1_b   = (const float*)d_in[13];
    const float* bna_g  = (const float*)d_in[14];
    const float* bna_b  = (const float*)d_in[15];
    const float* l2_W   = (const float*)d_in[16];
    const float* l2_b   = (const float*)d_in[17];
    const float* bnb_g  = (const float*)d_in[18];
    const float* bnb_b  = (const float*)d_in[19];
    const float* l3_W   = (const float*)d_in[20];
    const float* l3_b   = (const float*)d_in[21];
    float* out = (float*)d_out;

    // workspace layout (bytes), all sizes 256-aligned by construction
    char* w = (char*)d_ws;
    size_t off = 0;
    auto alloc = [&](size_t bytes) { void* p = w + off; off += (bytes + 255) & ~(size_t)255; return p; };
    u16* fc1w  = (u16*)alloc(294912ull * 2);     // (384,768)
    u16* fc2w  = (u16*)alloc(147456ull * 2);     // (384,384)
    u16* fcsw  = (u16*)alloc(2801664ull * 2);    // (7296,384)
    u16* gfcsw = (u16*)alloc(16809984ull * 2);   // (19,768,1152)
    u16* l1w   = (u16*)alloc(98304ull * 2);      // (128,768)
    u16* feau  = (u16*)alloc(3145728ull * 2);    // (4096,768)
    u16* hbuf  = (u16*)alloc(1572864ull * 2);    // (4096,384)
    u16* feaz  = (u16*)alloc(1572864ull * 2);    // (4096,384)
    u16* vecb  = (u16*)alloc(29884416ull * 2);   // (4096,7296)
    u16* attb  = (u16*)alloc(59768832ull * 2);   // (4096,19,768)
    u16* feav  = (u16*)alloc(3145728ull * 2);    // (4096,768)
    u16* h1b   = (u16*)alloc(524288ull * 2);     // (4096,128)
    float* h2f = (float*)alloc(131072ull * 4);   // (4096,32)
    (void)ws_size; (void)in_sizes; (void)n_in; (void)out_size;

    // K0: weight conversion (20152320 elements)
    cvt_weights_kernel<<<78720, 256, 0, stream>>>(fc1_W, fc2_W, fcs_W, gfcs_W, l1_W,
                                                  fc1w, fc2w, fcsw, gfcsw, l1w);
    // K1: fea_u
    feau_kernel<<<dim3(4096, 3), 256, 0, stream>>>(x, feau);
    // K2: fc1 + relu + bn
    gemm_bf16_kernel<EPI_RELU_BN><<<dim3(32, 3), 256, 0, stream>>>(feau, fc1w, fc1_b, bn1_g, bn1_b, hbuf, 768, 384);
    // K3: fc2
    gemm_bf16_kernel<EPI_BIAS><<<dim3(32, 3), 256, 0, stream>>>(hbuf, fc2w, fc2_b, nullptr, nullptr, feaz, 384, 384);
    // K4: vec (fcs stacked -> N=7296)
    gemm_bf16_kernel<EPI_BIAS><<<dim3(32, 57), 256, 0, stream>>>(feaz, fcsw, fcs_b, nullptr, nullptr, vecb, 384, 7296);
    // K5: att (batched over m)
    att_gemm_kernel<<<dim3(32, 6, 19), 256, 0, stream>>>(vecb, g, gfcsw, gfcs_b, attb);
    // K6: softmax over m + weighted sum with x
    softmax_feav_kernel<<<dim3(4096, 3), 256, 0, stream>>>(attb, x, feav);
    // K7: head l1 + relu + bn
    gemm_bf16_kernel<EPI_RELU_BN><<<dim3(32, 1), 256, 0, stream>>>(feav, l1w, l1_b, bna_g, bna_b, h1b, 768, 128);
    // K8: head l2 + relu + bn
    l2_kernel<<<512, 256, 0, stream>>>(h1b, l2_W, l2_b, bnb_g, bnb_b, h2f);
    // K9: head l3 -> out
    l3_kernel<<<320, 256, 0, stream>>>(h2f, l3_W, l3_b, out);
}

// Round 2
// 930.616 us; speedup vs baseline: 1.0408x; 1.0408x over previous
//
#include <hip/hip_runtime.h>

// ---------------------------------------------------------------------------
// classifier_selective_ts_with_g — round 1
//
// Algebraic fold: att[m] = feaz @ Wc[m]^T + g[m] @ W2[m]^T + bc[m]
//   where Wc[m] = W1[m] @ fcs[m]  (precomputed, stored in gfcs_eff cols 0..384)
//         W2[m] = gfcs_W[m][:,384:]  (gfcs_eff cols 384..1152)
//         bc[m] = gfcs_b[m] + W1[m] @ fcs_b[m]
// This deletes the standalone vec GEMM (23 GF + 60 MB traffic).
// att kernel A = [feaz (K<384) | g_bf16 (K>=384)], all global_load_lds when
// ws_size permits a g_bf16 buffer; otherwise in-loop fp32->bf16 fallback.
// ---------------------------------------------------------------------------

typedef unsigned short u16;
typedef unsigned int u32;
typedef long long i64;
typedef float f32x4 __attribute__((ext_vector_type(4)));
typedef __bf16 bf16x8 __attribute__((ext_vector_type(8)));

#define GPTR(p) ((const __attribute__((address_space(1))) void*)(p))
#define SPTR(p) ((__attribute__((address_space(3))) void*)(p))

__device__ __forceinline__ u16 f2bf(float f) {
    u32 u = __float_as_uint(f);
    u += 0x7fffu + ((u >> 16) & 1u);   // RNE; inputs finite
    return (u16)(u >> 16);
}
__device__ __forceinline__ float bf2f(u16 h) {
    return __uint_as_float(((u32)h) << 16);
}
__device__ __forceinline__ u32 pk2(float a, float b) {
    return (u32)f2bf(a) | ((u32)f2bf(b) << 16);
}

#define BNRS 0.9999950000374997f  // 1/sqrt(1+1e-5)

#define EPI_NONE    0
#define EPI_BIAS    1
#define EPI_RELU_BN 2

// ---------------------------------------------------------------------------
// Generic C = A @ B^T (+bias/+relu+bn); A: M x K (lda), B: N x K (ldb),
// C row stride ldc. Optional batch via blockIdx.z with element strides.
// Tiles 128x128xBK32, 4 waves of 64x64, mfma 16x16x32 bf16.
// ---------------------------------------------------------------------------
template <int EPI>
__global__ __launch_bounds__(256)
void gemm_bf16_kernel(const u16* __restrict__ A, i64 Abat, int lda,
                      const u16* __restrict__ B, i64 Bbat, int ldb,
                      const float* __restrict__ bias,
                      const float* __restrict__ bnG, const float* __restrict__ bnB,
                      u16* __restrict__ C, i64 Cbat, int ldc, int K)
{
    constexpr int BK = 32;
    __shared__ __align__(16) u16 lA[128 * BK];
    __shared__ __align__(16) u16 lB[128 * BK];

    const int z    = blockIdx.z;
    const int tid  = threadIdx.x;
    const int wave = tid >> 6;
    const int lane = tid & 63;
    const int bm   = blockIdx.x * 128;
    const int bn   = blockIdx.y * 128;
    const int wm   = (wave >> 1) * 64;
    const int wn   = (wave & 1) * 64;
    const int rl   = lane & 15;
    const int qk   = (lane >> 4) * 8;

    f32x4 acc[4][4] = {};

    const u16* Ab = A + (size_t)z * Abat + (size_t)bm * lda;
    const u16* Bb = B + (size_t)z * Bbat + (size_t)bn * ldb;

    for (int k0 = 0; k0 < K; k0 += BK) {
#pragma unroll
        for (int r = 0; r < 2; ++r) {
            const int c   = r * 256 + wave * 64 + lane;   // 8-bf16 chunk id
            const int row = c >> 2;
            const int kc  = (c & 3) << 3;
            const u16* sa = Ab + (size_t)row * lda + (k0 + kc);
            const u16* sb = Bb + (size_t)row * ldb + (k0 + kc);
            __builtin_amdgcn_global_load_lds(GPTR(sa), SPTR(&lA[(r * 256 + wave * 64) * 8]), 16, 0, 0);
            __builtin_amdgcn_global_load_lds(GPTR(sb), SPTR(&lB[(r * 256 + wave * 64) * 8]), 16, 0, 0);
        }
        __syncthreads();

        bf16x8 af[4], bfr[4];
#pragma unroll
        for (int i = 0; i < 4; ++i) af[i]  = *(const bf16x8*)&lA[(wm + i * 16 + rl) * BK + qk];
#pragma unroll
        for (int j = 0; j < 4; ++j) bfr[j] = *(const bf16x8*)&lB[(wn + j * 16 + rl) * BK + qk];
#pragma unroll
        for (int i = 0; i < 4; ++i)
#pragma unroll
            for (int j = 0; j < 4; ++j)
                acc[i][j] = __builtin_amdgcn_mfma_f32_16x16x32_bf16(af[i], bfr[j], acc[i][j], 0, 0, 0);
        __syncthreads();
    }

    u16* Cb = C + (size_t)z * Cbat;
    const int q4 = (lane >> 4) * 4;
#pragma unroll
    for (int j = 0; j < 4; ++j) {
        const int col = bn + wn + j * 16 + rl;
        float bsv = 0.f, scl = 1.f, sft = 0.f;
        if constexpr (EPI != EPI_NONE) bsv = bias[col];
        if constexpr (EPI == EPI_RELU_BN) { scl = bnG[col] * BNRS; sft = bnB[col]; }
#pragma unroll
        for (int i = 0; i < 4; ++i) {
            const int row0 = bm + wm + i * 16 + q4;
#pragma unroll
            for (int r = 0; r < 4; ++r) {
                float v = acc[i][j][r];
                if constexpr (EPI != EPI_NONE) v += bsv;
                if constexpr (EPI == EPI_RELU_BN) v = fmaxf(v, 0.f) * scl + sft;
                Cb[(size_t)(row0 + r) * ldc + col] = f2bf(v);
            }
        }
    }
}

// ---------------------------------------------------------------------------
// att path A: A = [feaz (lda 384) | g_bf16 (stride 14592)], all async staging
// grid: (32, 6, 19)
// ---------------------------------------------------------------------------
__global__ __launch_bounds__(256)
void att_gemm_a_kernel(const u16* __restrict__ feaz, const u16* __restrict__ gb,
                       const u16* __restrict__ W, const float* __restrict__ bc,
                       u16* __restrict__ att)
{
    constexpr int BK = 32, K = 1152;
    __shared__ __align__(16) u16 lA[128 * BK];
    __shared__ __align__(16) u16 lB[128 * BK];

    const int m    = blockIdx.z;
    const int tid  = threadIdx.x;
    const int wave = tid >> 6;
    const int lane = tid & 63;
    const int bm   = blockIdx.x * 128;
    const int bn   = blockIdx.y * 128;
    const int wm   = (wave >> 1) * 64;
    const int wn   = (wave & 1) * 64;
    const int rl   = lane & 15;
    const int qk   = (lane >> 4) * 8;

    f32x4 acc[4][4] = {};

    const u16* A1 = feaz + (size_t)bm * 384;
    const u16* A2 = gb + (size_t)bm * 14592 + m * 768;
    const u16* Bb = W + (size_t)m * 884736 + (size_t)bn * K;

    for (int k0 = 0; k0 < K; k0 += BK) {
#pragma unroll
        for (int r = 0; r < 2; ++r) {
            const int c   = r * 256 + wave * 64 + lane;
            const int row = c >> 2;
            const int kc  = (c & 3) << 3;
            const u16* sa = (k0 < 384)
                ? A1 + (size_t)row * 384 + (k0 + kc)
                : A2 + (size_t)row * 14592 + (k0 - 384 + kc);
            const u16* sb = Bb + (size_t)row * K + (k0 + kc);
            __builtin_amdgcn_global_load_lds(GPTR(sa), SPTR(&lA[(r * 256 + wave * 64) * 8]), 16, 0, 0);
            __builtin_amdgcn_global_load_lds(GPTR(sb), SPTR(&lB[(r * 256 + wave * 64) * 8]), 16, 0, 0);
        }
        __syncthreads();

        bf16x8 af[4], bfr[4];
#pragma unroll
        for (int i = 0; i < 4; ++i) af[i]  = *(const bf16x8*)&lA[(wm + i * 16 + rl) * BK + qk];
#pragma unroll
        for (int j = 0; j < 4; ++j) bfr[j] = *(const bf16x8*)&lB[(wn + j * 16 + rl) * BK + qk];
#pragma unroll
        for (int i = 0; i < 4; ++i)
#pragma unroll
            for (int j = 0; j < 4; ++j)
                acc[i][j] = __builtin_amdgcn_mfma_f32_16x16x32_bf16(af[i], bfr[j], acc[i][j], 0, 0, 0);
        __syncthreads();
    }

    const int q4 = (lane >> 4) * 4;
#pragma unroll
    for (int j = 0; j < 4; ++j) {
        const int col = bn + wn + j * 16 + rl;
        const float bsv = bc[m * 768 + col];
#pragma unroll
        for (int i = 0; i < 4; ++i) {
            const int row0 = bm + wm + i * 16 + q4;
#pragma unroll
            for (int r = 0; r < 4; ++r)
                att[(size_t)(row0 + r) * 14592 + m * 768 + col] = f2bf(acc[i][j][r] + bsv);
        }
    }
}

// ---------------------------------------------------------------------------
// att path B (small-ws fallback): g fp32 converted in-loop
// ---------------------------------------------------------------------------
__global__ __launch_bounds__(256)
void att_gemm_b_kernel(const u16* __restrict__ feaz, const float* __restrict__ g,
                       const u16* __restrict__ W, const float* __restrict__ bc,
                       u16* __restrict__ att)
{
    constexpr int BK = 32, K = 1152;
    __shared__ __align__(16) u16 lA[128 * BK];
    __shared__ __align__(16) u16 lB[128 * BK];

    const int m    = blockIdx.z;
    const int tid  = threadIdx.x;
    const int wave = tid >> 6;
    const int lane = tid & 63;
    const int bm   = blockIdx.x * 128;
    const int bn   = blockIdx.y * 128;
    const int wm   = (wave >> 1) * 64;
    const int wn   = (wave & 1) * 64;
    const int rl   = lane & 15;
    const int qk   = (lane >> 4) * 8;

    f32x4 acc[4][4] = {};

    const u16* A1 = feaz + (size_t)bm * 384;
    const float* Ag = g + (size_t)bm * 14592 + m * 768;
    const u16* Bb = W + (size_t)m * 884736 + (size_t)bn * K;

    for (int k0 = 0; k0 < K; k0 += BK) {
        if (k0 < 384) {
#pragma unroll
            for (int r = 0; r < 2; ++r) {
                const int c   = r * 256 + wave * 64 + lane;
                const int row = c >> 2;
                const int kc  = (c & 3) << 3;
                const u16* sa = A1 + (size_t)row * 384 + (k0 + kc);
                __builtin_amdgcn_global_load_lds(GPTR(sa), SPTR(&lA[(r * 256 + wave * 64) * 8]), 16, 0, 0);
            }
        } else {
#pragma unroll
            for (int r = 0; r < 2; ++r) {
                const int c   = r * 256 + tid;
                const int row = c >> 2;
                const int kc  = (c & 3) << 3;
                const float* sf = Ag + (size_t)row * 14592 + (k0 - 384 + kc);
                const float4 f0 = *(const float4*)sf;
                const float4 f1 = *(const float4*)(sf + 4);
                uint4 pk;
                pk.x = pk2(f0.x, f0.y);  pk.y = pk2(f0.z, f0.w);
                pk.z = pk2(f1.x, f1.y);  pk.w = pk2(f1.z, f1.w);
                *(uint4*)&lA[c * 8] = pk;
            }
        }
#pragma unroll
        for (int r = 0; r < 2; ++r) {
            const int c   = r * 256 + wave * 64 + lane;
            const int row = c >> 2;
            const int kc  = (c & 3) << 3;
            const u16* sb = Bb + (size_t)row * K + (k0 + kc);
            __builtin_amdgcn_global_load_lds(GPTR(sb), SPTR(&lB[(r * 256 + wave * 64) * 8]), 16, 0, 0);
        }
        __syncthreads();

        bf16x8 af[4], bfr[4];
#pragma unroll
        for (int i = 0; i < 4; ++i) af[i]  = *(const bf16x8*)&lA[(wm + i * 16 + rl) * BK + qk];
#pragma unroll
        for (int j = 0; j < 4; ++j) bfr[j] = *(const bf16x8*)&lB[(wn + j * 16 + rl) * BK + qk];
#pragma unroll
        for (int i = 0; i < 4; ++i)
#pragma unroll
            for (int j = 0; j < 4; ++j)
                acc[i][j] = __builtin_amdgcn_mfma_f32_16x16x32_bf16(af[i], bfr[j], acc[i][j], 0, 0, 0);
        __syncthreads();
    }

    const int q4 = (lane >> 4) * 4;
#pragma unroll
    for (int j = 0; j < 4; ++j) {
        const int col = bn + wn + j * 16 + rl;
        const float bsv = bc[m * 768 + col];
#pragma unroll
        for (int i = 0; i < 4; ++i) {
            const int row0 = bm + wm + i * 16 + q4;
#pragma unroll
            for (int r = 0; r < 4; ++r)
                att[(size_t)(row0 + r) * 14592 + m * 768 + col] = f2bf(acc[i][j][r] + bsv);
        }
    }
}

// ---------------------------------------------------------------------------
// Elementwise / conversion kernels
// ---------------------------------------------------------------------------

// flat fp32->bf16: fc1 (294912) | fc2 (147456) | l1 (98304); x8 per thread
__global__ __launch_bounds__(256)
void cvt_flat_kernel(const float* __restrict__ s0, const float* __restrict__ s1,
                     const float* __restrict__ s2,
                     u16* __restrict__ d0, u16* __restrict__ d1, u16* __restrict__ d2)
{
    const int i = blockIdx.x * 256 + threadIdx.x;   // 67584 chunks of 8
    const float* s; u16* d; int off;
    if (i < 36864)      { s = s0; d = d0; off = i; }
    else if (i < 55296) { s = s1; d = d1; off = i - 36864; }
    else                { s = s2; d = d2; off = i - 55296; }
    const float4 f0 = *(const float4*)(s + off * 8);
    const float4 f1 = *(const float4*)(s + off * 8 + 4);
    uint4 pk; pk.x = pk2(f0.x, f0.y); pk.y = pk2(f0.z, f0.w);
    pk.z = pk2(f1.x, f1.y); pk.w = pk2(f1.z, f1.w);
    *(uint4*)(d + off * 8) = pk;
}

// gfcs split-convert: rows 19*768, cols 0..384 -> W1 bf16, 384..1152 -> gfcs_eff
__global__ __launch_bounds__(256)
void cvt_gfcs_kernel(const float* __restrict__ gfcs, u16* __restrict__ w1,
                     u16* __restrict__ geff)
{
    const int i = blockIdx.x * 256 + threadIdx.x;   // 14592 * 144 chunks
    const int r = i / 144, c = i - r * 144;
    const float* s = gfcs + (size_t)r * 1152 + c * 8;
    const float4 f0 = *(const float4*)s;
    const float4 f1 = *(const float4*)(s + 4);
    uint4 pk; pk.x = pk2(f0.x, f0.y); pk.y = pk2(f0.z, f0.w);
    pk.z = pk2(f1.x, f1.y); pk.w = pk2(f1.z, f1.w);
    u16* d = (c < 48) ? (w1 + (size_t)r * 384 + c * 8)
                      : (geff + (size_t)r * 1152 + c * 8);
    *(uint4*)d = pk;
}

// fcs transpose+convert: fcswT[m][d][e] = fcs[m][e][d]
__global__ __launch_bounds__(256)
void cvt_fcsT_kernel(const float* __restrict__ fcs, u16* __restrict__ fcswT)
{
    const int i = blockIdx.x * 256 + threadIdx.x;   // 19*384*48 chunks
    const int m = i / 18432, rem = i - m * 18432;
    const int d = rem / 48, e8 = (rem - d * 48) * 8;
    const float* s = fcs + (size_t)m * 147456 + (size_t)e8 * 384 + d;
    float f[8];
#pragma unroll
    for (int j = 0; j < 8; ++j) f[j] = s[j * 384];
    uint4 pk; pk.x = pk2(f[0], f[1]); pk.y = pk2(f[2], f[3]);
    pk.z = pk2(f[4], f[5]); pk.w = pk2(f[6], f[7]);
    *(uint4*)(fcswT + (size_t)m * 147456 + (size_t)d * 384 + e8) = pk;
}

// g fp32 -> bf16 flat (path A)
__global__ __launch_bounds__(256)
void cvt_g_kernel(const float* __restrict__ g, u16* __restrict__ gb)
{
    const size_t i = ((size_t)blockIdx.x * 256 + threadIdx.x) * 8;  // 59768832 elems
    const float4 f0 = *(const float4*)(g + i);
    const float4 f1 = *(const float4*)(g + i + 4);
    uint4 pk; pk.x = pk2(f0.x, f0.y); pk.y = pk2(f0.z, f0.w);
    pk.z = pk2(f1.x, f1.y); pk.w = pk2(f1.z, f1.w);
    *(uint4*)(gb + i) = pk;
}

// bc[m][o] = gfcs_b[m*768+o] + sum_d gfcs[m][o][d] * fcs_b[m][d]   (one wave per (m,o))
__global__ __launch_bounds__(256)
void bc_kernel(const float* __restrict__ gfcs, const float* __restrict__ gfcs_b,
               const float* __restrict__ fcs_b, float* __restrict__ bc)
{
    const int widx = blockIdx.x * 4 + (threadIdx.x >> 6);   // 14592 waves
    const int lane = threadIdx.x & 63;
    const int m = widx / 768, o = widx - m * 768;
    const float* wr = gfcs + (size_t)m * 884736 + (size_t)o * 1152;
    const float* fb = fcs_b + m * 384;
    float a = 0.f;
#pragma unroll
    for (int t = 0; t < 6; ++t) a += wr[lane + t * 64] * fb[lane + t * 64];
#pragma unroll
    for (int off = 32; off > 0; off >>= 1) a += __shfl_down(a, off, 64);
    if (lane == 0) bc[widx] = gfcs_b[widx] + a;
}

// fea_u = sum_m x3 ; block=192, 4 outputs/thread
__global__ __launch_bounds__(192)
void feau_kernel(const float* __restrict__ x, u16* __restrict__ feau)
{
    const int b = blockIdx.x;
    const int o = threadIdx.x * 4;
    const float* xp = x + (size_t)b * 14592 + o;
    float4 s = {0.f, 0.f, 0.f, 0.f};
#pragma unroll
    for (int m = 0; m < 19; ++m) {
        const float4 v = *(const float4*)(xp + m * 768);
        s.x += v.x; s.y += v.y; s.z += v.z; s.w += v.w;
    }
    ushort4 r; r.x = f2bf(s.x); r.y = f2bf(s.y); r.z = f2bf(s.z); r.w = f2bf(s.w);
    *(ushort4*)(feau + (size_t)b * 768 + o) = r;
}

// softmax over m + weighted x sum; block=192, 4 outputs/thread
__global__ __launch_bounds__(192)
void softmax_feav_kernel(const u16* __restrict__ att, const float* __restrict__ x,
                         u16* __restrict__ feav)
{
    const int b = blockIdx.x;
    const int o = threadIdx.x * 4;
    const u16* ap   = att + (size_t)b * 14592 + o;
    const float* xp = x   + (size_t)b * 14592 + o;
    float4 l[19];
    float4 mx = {-1e30f, -1e30f, -1e30f, -1e30f};
#pragma unroll
    for (int m = 0; m < 19; ++m) {
        const ushort4 u = *(const ushort4*)(ap + m * 768);
        l[m].x = bf2f(u.x); l[m].y = bf2f(u.y); l[m].z = bf2f(u.z); l[m].w = bf2f(u.w);
        mx.x = fmaxf(mx.x, l[m].x); mx.y = fmaxf(mx.y, l[m].y);
        mx.z = fmaxf(mx.z, l[m].z); mx.w = fmaxf(mx.w, l[m].w);
    }
    float4 s = {0.f, 0.f, 0.f, 0.f};
#pragma unroll
    for (int m = 0; m < 19; ++m) {
        l[m].x = __expf(l[m].x - mx.x); s.x += l[m].x;
        l[m].y = __expf(l[m].y - mx.y); s.y += l[m].y;
        l[m].z = __expf(l[m].z - mx.z); s.z += l[m].z;
        l[m].w = __expf(l[m].w - mx.w); s.w += l[m].w;
    }
    const float4 inv = {1.f / s.x, 1.f / s.y, 1.f / s.z, 1.f / s.w};
    float4 a = {0.f, 0.f, 0.f, 0.f};
#pragma unroll
    for (int m = 0; m < 19; ++m) {
        const float4 v = *(const float4*)(xp + m * 768);
        a.x += v.x * l[m].x; a.y += v.y * l[m].y;
        a.z += v.z * l[m].z; a.w += v.w * l[m].w;
    }
    ushort4 r;
    r.x = f2bf(a.x * inv.x); r.y = f2bf(a.y * inv.y);
    r.z = f2bf(a.z * inv.z); r.w = f2bf(a.w * inv.w);
    *(ushort4*)(feav + (size_t)b * 768 + o) = r;
}

__global__ __launch_bounds__(256)
void l2_kernel(const u16* __restrict__ h1, const float* __restrict__ W,
               const float* __restrict__ bias, const float* __restrict__ bg,
               const float* __restrict__ bb, float* __restrict__ h2)
{
    const int idx = blockIdx.x * 256 + threadIdx.x;   // 4096*32
    const int b = idx >> 5, n = idx & 31;
    const u16* hp  = h1 + (size_t)b * 128;
    const float* wp = W + n * 128;
    float a = bias[n];
#pragma unroll 8
    for (int k = 0; k < 128; ++k) a += bf2f(hp[k]) * wp[k];
    a = fmaxf(a, 0.f) * (bg[n] * BNRS) + bb[n];
    h2[idx] = a;
}

__global__ __launch_bounds__(256)
void l3_kernel(const float* __restrict__ h2, const float* __restrict__ W,
               const float* __restrict__ bias, float* __restrict__ out)
{
    const int idx = blockIdx.x * 256 + threadIdx.x;   // 4096*20
    const int b = idx / 20, n = idx - b * 20;
    const float* hp = h2 + (size_t)b * 32;
    const float* wp = W + n * 32;
    float a = bias[n];
#pragma unroll
    for (int k = 0; k < 32; ++k) a += hp[k] * wp[k];
    out[idx] = a;
}

// ---------------------------------------------------------------------------
extern "C" void kernel_launch(void* const* d_in, const int* in_sizes, int n_in,
                              void* d_out, int out_size, void* d_ws, size_t ws_size,
                              hipStream_t stream)
{
    const float* x      = (const float*)d_in[0];
    const float* g      = (const float*)d_in[1];
    const float* fc1_W  = (const float*)d_in[2];
    const float* fc1_b  = (const float*)d_in[3];
    const float* bn1_g  = (const float*)d_in[4];
    const float* bn1_b  = (const float*)d_in[5];
    const float* fc2_W  = (const float*)d_in[6];
    const float* fc2_b  = (const float*)d_in[7];
    const float* fcs_W  = (const float*)d_in[8];
    const float* fcs_b  = (const float*)d_in[9];
    const float* gfcs_W = (const float*)d_in[10];
    const float* gfcs_b = (const float*)d_in[11];
    const float* l1_W   = (const float*)d_in[12];
    const float* l1_b   = (const float*)d_in[13];
    const float* bna_g  = (const float*)d_in[14];
    const float* bna_b  = (const float*)d_in[15];
    const float* l2_W   = (const float*)d_in[16];
    const float* l2_b   = (const float*)d_in[17];
    const float* bnb_g  = (const float*)d_in[18];
    const float* bnb_b  = (const float*)d_in[19];
    const float* l3_W   = (const float*)d_in[20];
    const float* l3_b   = (const float*)d_in[21];
    float* out = (float*)d_out;
    (void)in_sizes; (void)n_in; (void)out_size;

    char* w = (char*)d_ws;
    size_t off = 0;
    auto alloc = [&](size_t bytes) { void* p = w + off; off += (bytes + 255) & ~(size_t)255; return p; };
    u16* fc1w  = (u16*)alloc(294912ull * 2);     // (384,768)
    u16* fc2w  = (u16*)alloc(147456ull * 2);     // (384,384)
    u16* l1w   = (u16*)alloc(98304ull * 2);      // (128,768)
    u16* fcswT = (u16*)alloc(2801664ull * 2);    // (19,384,384) transposed
    u16* w1bf  = (u16*)alloc(5603328ull * 2);    // (19,768,384)
    u16* geff  = (u16*)alloc(16809984ull * 2);   // (19,768,1152) [Wc | W2]
    float* bcb = (float*)alloc(14592ull * 4);    // (19,768)
    u16* feau  = (u16*)alloc(3145728ull * 2);    // (4096,768)
    u16* hbuf  = (u16*)alloc(1572864ull * 2);    // (4096,384)
    u16* feaz  = (u16*)alloc(1572864ull * 2);    // (4096,384)
    u16* attb  = (u16*)alloc(59768832ull * 2);   // (4096,19,768)
    u16* feav  = (u16*)alloc(3145728ull * 2);    // (4096,768)
    u16* h1b   = (u16*)alloc(524288ull * 2);     // (4096,128)
    float* h2f = (float*)alloc(131072ull * 4);   // (4096,32)
    u16* gbf   = (u16*)alloc(59768832ull * 2);   // (4096,19*768) path A only
    const bool useA = (ws_size >= off);

    // weight prep
    cvt_flat_kernel<<<264, 256, 0, stream>>>(fc1_W, fc2_W, l1_W, fc1w, fc2w, l1w);
    cvt_gfcs_kernel<<<8208, 256, 0, stream>>>(gfcs_W, w1bf, geff);
    cvt_fcsT_kernel<<<1368, 256, 0, stream>>>(fcs_W, fcswT);
    bc_kernel<<<3648, 256, 0, stream>>>(gfcs_W, gfcs_b, fcs_b, bcb);
    // Wc[m] = W1[m] @ fcs[m] -> geff cols 0..384
    gemm_bf16_kernel<EPI_NONE><<<dim3(6, 3, 19), 256, 0, stream>>>(
        w1bf, 294912, 384, fcswT, 147456, 384, nullptr, nullptr, nullptr,
        geff, 884736, 1152, 384);
    if (useA) cvt_g_kernel<<<29184, 256, 0, stream>>>(g, gbf);

    // trunk
    feau_kernel<<<4096, 192, 0, stream>>>(x, feau);
    gemm_bf16_kernel<EPI_RELU_BN><<<dim3(32, 3), 256, 0, stream>>>(
        feau, 0, 768, fc1w, 0, 768, fc1_b, bn1_g, bn1_b, hbuf, 0, 384, 768);
    gemm_bf16_kernel<EPI_BIAS><<<dim3(32, 3), 256, 0, stream>>>(
        hbuf, 0, 384, fc2w, 0, 384, fc2_b, nullptr, nullptr, feaz, 0, 384, 384);

    // att
    if (useA)
        att_gemm_a_kernel<<<dim3(32, 6, 19), 256, 0, stream>>>(feaz, gbf, geff, bcb, attb);
    else
        att_gemm_b_kernel<<<dim3(32, 6, 19), 256, 0, stream>>>(feaz, g, geff, bcb, attb);
    softmax_feav_kernel<<<4096, 192, 0, stream>>>(attb, x, feav);

    // head
    gemm_bf16_kernel<EPI_RELU_BN><<<dim3(32, 1), 256, 0, stream>>>(
        feav, 0, 768, l1w, 0, 768, l1_b, bna_g, bna_b, h1b, 0, 128, 768);
    l2_kernel<<<512, 256, 0, stream>>>(h1b, l2_W, l2_b, bnb_g, bnb_b, h2f);
    l3_kernel<<<320, 256, 0, stream>>>(h2f, l3_W, l3_b, out);
}